// Round 1
// baseline (1434.055 us; speedup 1.0000x reference)
//
#include <hip/hip_runtime.h>
#include <hip/hip_bf16.h>
#include <cstdint>
#include <cstddef>

typedef __bf16 bf16x8 __attribute__((ext_vector_type(8)));
typedef float f32x4 __attribute__((ext_vector_type(4)));

constexpr int kN = 16384;   // nodes
constexpr int kD = 64;      // feature dim

// ---------------------------------------------------------------------------
// Kernel A: T = X @ W_agg  (fp32 compute), stored bf16, pre-swizzled into
// MFMA 16x16x32 B-fragment order:
//   element (k, n) lives at vec-slot ((kb*4 + nb)*4 + kq)*16 + ln, lane-elem j
//   where kb=k>>5, kq=(k>>3)&3, j=k&7, nb=n>>4, ln=n&15.
// Each thread computes 8 consecutive k for one n -> exactly one 16-B store.
// ---------------------------------------------------------------------------
__global__ __launch_bounds__(256) void xw_swizzle_kernel(
    const float* __restrict__ X, const float* __restrict__ W,
    __bf16* __restrict__ Tsw) {
  __shared__ float Ws[kD * kD];
  const int tid = threadIdx.x;
#pragma unroll
  for (int i = 0; i < 16; ++i) Ws[i * 256 + tid] = W[i * 256 + tid];
  __syncthreads();

  const int t = blockIdx.x * 256 + tid;
  const int n = t & 63;            // output column
  const int kbase = (t >> 6) << 3; // first of 8 output rows (k of T)

  float acc[8];
#pragma unroll
  for (int i = 0; i < 8; ++i) acc[i] = 0.f;

  const f32x4* X4 = (const f32x4*)X;
#pragma unroll 4
  for (int d4 = 0; d4 < 16; ++d4) {
    const float w0 = Ws[(d4 * 4 + 0) * 64 + n];
    const float w1 = Ws[(d4 * 4 + 1) * 64 + n];
    const float w2 = Ws[(d4 * 4 + 2) * 64 + n];
    const float w3 = Ws[(d4 * 4 + 3) * 64 + n];
#pragma unroll
    for (int i = 0; i < 8; ++i) {
      f32x4 x = X4[(size_t)(kbase + i) * 16 + d4]; // wave-broadcast load
      acc[i] += x[0] * w0 + x[1] * w1 + x[2] * w2 + x[3] * w3;
    }
  }

  const int kb = kbase >> 5, kq = (kbase >> 3) & 3;
  const int nb = n >> 4, ln = n & 15;
  const int slot = ((kb * 4 + nb) * 4 + kq) * 16 + ln;
  bf16x8 v;
#pragma unroll
  for (int i = 0; i < 8; ++i) v[i] = (__bf16)acc[i];
  ((bf16x8*)Tsw)[slot] = v;
}

// ---------------------------------------------------------------------------
// Kernel B: P[half] = A_hat[:, half] @ T[half, :]   (bf16 MFMA, fp32 accum)
// Wave owns a 16-row x 64-col strip. A loaded straight from global fp32
// (each element exactly once), converted to bf16 in-register. B fragments
// come pre-swizzled from Tsw (one dwordx4 per lane, L2-hot).
// Split-K=2 for occupancy (512 blocks -> 2 blocks/CU); distance-2 register
// prefetch for HBM latency hiding. No LDS, no barriers.
// ---------------------------------------------------------------------------
__global__ __launch_bounds__(256, 2) void agg_gemm_kernel(
    const float* __restrict__ A, const __bf16* __restrict__ Tsw,
    float* __restrict__ P) {
  const int lane = threadIdx.x & 63;
  const int wave = threadIdx.x >> 6;
  const int quad = lane >> 4;
  const int ln = lane & 15;

  const int half = blockIdx.x & 1;
  const int rowBase = (blockIdx.x >> 1) * 64 + wave * 16;
  const int kStart = half * (kN / 2);
  constexpr int KIT = (kN / 2) / 32; // 256 K-steps of 32

  // A-fragment: lane holds A[rowBase + ln][k0 + quad*8 + j], j=0..7
  const float* arow = A + (size_t)(rowBase + ln) * kN + kStart + quad * 8;
  // B-fragment: vec-slot (kb*4 + nb)*64 + lane
  const bf16x8* bbase = (const bf16x8*)Tsw + (size_t)(kStart >> 5) * 256 + lane;

  f32x4 acc[4] = {};

  f32x4 a0[2], a1[2];
  bf16x8 bb[2][4];

  // prologue: iterations 0 and 1
#pragma unroll
  for (int p = 0; p < 2; ++p) {
    const f32x4* ap = (const f32x4*)(arow + p * 32);
    a0[p] = __builtin_nontemporal_load(ap);
    a1[p] = __builtin_nontemporal_load(ap + 1);
#pragma unroll
    for (int nb = 0; nb < 4; ++nb)
      bb[p][nb] = bbase[p * 256 + nb * 64];
  }

#pragma unroll 2
  for (int it = 0; it < KIT; ++it) {
    const int s = it & 1;

    // fp32 -> bf16 A fragment (RNE via __bf16 cast)
    bf16x8 af;
#pragma unroll
    for (int j = 0; j < 4; ++j) af[j] = (__bf16)a0[s][j];
#pragma unroll
    for (int j = 0; j < 4; ++j) af[4 + j] = (__bf16)a1[s][j];

    bf16x8 b0 = bb[s][0], b1 = bb[s][1], b2 = bb[s][2], b3 = bb[s][3];

    acc[0] = __builtin_amdgcn_mfma_f32_16x16x32_bf16(af, b0, acc[0], 0, 0, 0);
    acc[1] = __builtin_amdgcn_mfma_f32_16x16x32_bf16(af, b1, acc[1], 0, 0, 0);
    acc[2] = __builtin_amdgcn_mfma_f32_16x16x32_bf16(af, b2, acc[2], 0, 0, 0);
    acc[3] = __builtin_amdgcn_mfma_f32_16x16x32_bf16(af, b3, acc[3], 0, 0, 0);

    // distance-2 prefetch into the slot just consumed
    if (it + 2 < KIT) {
      const f32x4* ap = (const f32x4*)(arow + (size_t)(it + 2) * 32);
      a0[s] = __builtin_nontemporal_load(ap);
      a1[s] = __builtin_nontemporal_load(ap + 1);
#pragma unroll
      for (int nb = 0; nb < 4; ++nb)
        bb[s][nb] = bbase[(size_t)(it + 2) * 256 + nb * 64];
    }
  }

  // write fp32 partial tile: C/D layout col=lane&15, row=quad*4+reg
  float* Pout = P + (size_t)half * ((size_t)kN * kD);
#pragma unroll
  for (int nb = 0; nb < 4; ++nb) {
#pragma unroll
    for (int r = 0; r < 4; ++r) {
      const int row = rowBase + quad * 4 + r;
      const int col = nb * 16 + ln;
      Pout[(size_t)row * kD + col] = acc[nb][r];
    }
  }
}

// ---------------------------------------------------------------------------
// Kernel C: out = w * relu(P0 + P1) + (1 - w) * X
// ---------------------------------------------------------------------------
__global__ __launch_bounds__(256) void combine_kernel(
    const float* __restrict__ P, const float* __restrict__ X,
    const float* __restrict__ w, float* __restrict__ out) {
  const int e4 = blockIdx.x * 256 + threadIdx.x; // float4 index
  const f32x4 p0 = ((const f32x4*)P)[e4];
  const f32x4 p1 = ((const f32x4*)(P + (size_t)kN * kD))[e4];
  const f32x4 x = ((const f32x4*)X)[e4];
  const float wr = w[e4 >> 4]; // (e4*4)/64
  f32x4 o;
#pragma unroll
  for (int j = 0; j < 4; ++j) {
    float s = p0[j] + p1[j];
    s = s > 0.f ? s : 0.f;
    o[j] = wr * s + (1.f - wr) * x[j];
  }
  ((f32x4*)out)[e4] = o;
}

// ---------------------------------------------------------------------------
extern "C" void kernel_launch(void* const* d_in, const int* in_sizes, int n_in,
                              void* d_out, int out_size, void* d_ws, size_t ws_size,
                              hipStream_t stream) {
  const float* X = (const float*)d_in[0];     // [16384, 64]
  const float* A = (const float*)d_in[1];     // [16384, 16384]
  const float* w = (const float*)d_in[2];     // [16384]
  const float* W = (const float*)d_in[3];     // [64, 64]
  float* out = (float*)d_out;

  // ws layout: [0, 2MB) Tsw (bf16 swizzled), [2MB, 10MB) split-K partials
  __bf16* Tsw = (__bf16*)d_ws;
  float* P = (float*)((char*)d_ws + (size_t)2 * 1024 * 1024);

  xw_swizzle_kernel<<<512, 256, 0, stream>>>(X, W, Tsw);
  agg_gemm_kernel<<<512, 256, 0, stream>>>(A, Tsw, P);
  combine_kernel<<<1024, 256, 0, stream>>>(P, X, w, out);
}